// Round 4
// baseline (158.220 us; speedup 1.0000x reference)
//
#include <hip/hip_runtime.h>

typedef __fp16 half8   __attribute__((ext_vector_type(8)));
typedef __fp16 half2v  __attribute__((ext_vector_type(2)));
typedef float  float4v __attribute__((ext_vector_type(4)));

#define SCALE 2.88539008177792681f   // 2*log2(e): folded into W_in,b_in so MFMA yields a' = 2a*log2(e)

#if defined(__has_builtin) && __has_builtin(__builtin_amdgcn_fdot2)
#define DOT2(a, b, c) __builtin_amdgcn_fdot2((a), (b), (c), false)
#else
#define DOT2(a, b, c) ((c) + (float)(a).x * (float)(b).x + (float)(a).y * (float)(b).y)
#endif

// 2 batch rows per block, grid = batch/2 = 2048 = 8 blocks/CU: every block
// resident in one dispatch round (no turnover), setup amortized over 2 rows.
// __launch_bounds__(256,8) pins VGPR<=64 so 8 waves/SIMD actually fit.
//
// GEMM1 via MFMA 16x16x32_f16, TRANSPOSED: D[r][win] = W_in*Xwin^T + bias.
//   A = W_in (lane&15 = r-in-tile, k = 8*quad+j; k>=10 zero) — constant, preloaded.
//   B = window data (lane&15 = win-in-tile): lane reads sx[2n+8q .. +7] — im2col free.
//   C = bias (f32-exact add inside the MFMA).
// tanh = 1 - 2*rcp(1+exp2(a')); outer 64->2 via v_dot2_f32_f16 + 2-stage butterfly.
__global__ __launch_bounds__(256, 8) void pe_mfma2(
    const float* __restrict__ x, const float* __restrict__ W_in,
    const float* __restrict__ b_in, const float* __restrict__ W_out,
    float* __restrict__ out, int batch)
{
    __shared__ __align__(16) float sx[2][1056];  // sx[r][i] = x[row_r][(i-4) mod 1024]; tail zero-pad
    __shared__ __align__(16) float sWin[640];
    __shared__ __align__(16) float sWout[128];
    __shared__ __align__(16) float sb[64];

    const int t    = threadIdx.x;
    const int lane = t & 63;
    const int wv   = t >> 6;
    const int col  = lane & 15;
    const int quad = lane >> 4;
    const int row0 = 2 * blockIdx.x;
    const int nrows = (batch - row0 >= 2) ? 2 : 1;

    // ---- stage rows + weights (coalesced float4) ----
    {
        const float* xr0 = x + (size_t)row0 * 1024;
        float4 v0 = reinterpret_cast<const float4*>(xr0)[t];
        reinterpret_cast<float4*>(sx[0] + 4)[t] = v0;
        if (t < 4) { sx[0][t] = xr0[1020 + t]; sx[0][1028 + t] = xr0[t]; }
        if (t >= 8 && t < 32) { sx[0][1024 + t] = 0.f; sx[1][1024 + t] = 0.f; }
        if (nrows == 2) {
            const float* xr1 = xr0 + 1024;
            float4 v1 = reinterpret_cast<const float4*>(xr1)[t];
            reinterpret_cast<float4*>(sx[1] + 4)[t] = v1;
            if (t < 4) { sx[1][t] = xr1[1020 + t]; sx[1][1028 + t] = xr1[t]; }
        }
    }
    if (t < 160)
        reinterpret_cast<float4*>(sWin)[t] = reinterpret_cast<const float4*>(W_in)[t];
    else if (t >= 192 && t < 224)
        reinterpret_cast<float4*>(sWout)[t - 192] = reinterpret_cast<const float4*>(W_out)[t - 192];
    else if (t >= 224 && t < 240)
        reinterpret_cast<float4*>(sb)[t - 224] = reinterpret_cast<const float4*>(b_in)[t - 224];
    __syncthreads();

    // ---- per-lane constant fragments (shared by both rows) ----
    half8  Af[4];        // W_in * SCALE, 4 M-tiles of r
    float4v Cb[4];       // bias * SCALE (f32, exact)
    half2v Wp[4][2][2];  // W_out packed pairs [t4][pair][g], r = 16*t4+4*quad+2*pair
    #pragma unroll
    for (int t4 = 0; t4 < 4; ++t4) {
        const int r = 16 * t4 + col;
        #pragma unroll
        for (int j = 0; j < 8; ++j) {
            const int k = 8 * quad + j;
            Af[t4][j] = (__fp16)((k < 10) ? sWin[r * 10 + k] * SCALE : 0.f);
        }
        const int rb = 16 * t4 + 4 * quad;
        #pragma unroll
        for (int e = 0; e < 4; ++e) Cb[t4][e] = sb[rb + e] * SCALE;
        #pragma unroll
        for (int p = 0; p < 2; ++p) {
            const int r0 = rb + 2 * p;
            #pragma unroll
            for (int g = 0; g < 2; ++g)
                Wp[t4][p][g] = __builtin_amdgcn_cvt_pkrtz(sWout[g * 64 + r0], sWout[g * 64 + r0 + 1]);
        }
    }

    for (int row = 0; row < nrows; ++row) {
        const float* sxr = sx[row];
        float* orow = out + (size_t)(row0 + row) * 1024;

        #pragma unroll 2
        for (int it = 0; it < 8; ++it) {
            const int tile = wv * 8 + it;
            const int n    = tile * 16 + col;      // this lane's window
            const int base = 2 * n + 8 * quad;     // sx index of this lane's k-slice

            half8 Bf;
            #pragma unroll
            for (int p = 0; p < 4; ++p) {          // 4x ds_read_b64
                const float2 xv = *reinterpret_cast<const float2*>(sxr + base + 2 * p);
                const half2v h = __builtin_amdgcn_cvt_pkrtz(xv.x, xv.y);
                Bf[2 * p]     = h.x;
                Bf[2 * p + 1] = h.y;
            }

            float4v D[4];
            #pragma unroll
            for (int t4 = 0; t4 < 4; ++t4)
                D[t4] = __builtin_amdgcn_mfma_f32_16x16x32_f16(Af[t4], Bf, Cb[t4], 0, 0, 0);

            float g0 = 0.f, g1 = 0.f;
            #pragma unroll
            for (int t4 = 0; t4 < 4; ++t4) {
                float th[4];
                #pragma unroll
                for (int e = 0; e < 4; ++e) {
                    const float ex = __builtin_amdgcn_exp2f(D[t4][e]);   // e^{2a}
                    th[e] = fmaf(-2.f, __builtin_amdgcn_rcpf(1.f + ex), 1.f);
                }
                const half2v y01 = __builtin_amdgcn_cvt_pkrtz(th[0], th[1]);
                const half2v y23 = __builtin_amdgcn_cvt_pkrtz(th[2], th[3]);
                g0 = DOT2(y01, Wp[t4][0][0], g0);
                g0 = DOT2(y23, Wp[t4][1][0], g0);
                g1 = DOT2(y01, Wp[t4][0][1], g1);
                g1 = DOT2(y23, Wp[t4][1][1], g1);
            }

            g0 += __shfl_xor(g0, 16, 64);
            g0 += __shfl_xor(g0, 32, 64);
            g1 += __shfl_xor(g1, 16, 64);
            g1 += __shfl_xor(g1, 32, 64);

            if (quad == 0) {
                const float2 xr = *reinterpret_cast<const float2*>(sxr + 4 + 2 * n);
                float2 o;
                o.x = xr.x + g0;
                o.y = xr.y + g1;
                *reinterpret_cast<float2*>(orow + 2 * n) = o;
            }
        }
    }
}

extern "C" void kernel_launch(void* const* d_in, const int* in_sizes, int n_in,
                              void* d_out, int out_size, void* d_ws, size_t ws_size,
                              hipStream_t stream) {
    const float* x     = (const float*)d_in[0];
    const float* W_in  = (const float*)d_in[1];
    const float* b_in  = (const float*)d_in[2];
    const float* W_out = (const float*)d_in[3];
    // d_in[4] = idx — gather is analytically (2n-4+f) mod 1024
    float* out = (float*)d_out;
    const int batch = in_sizes[0] / 1024;
    const int grid  = (batch + 1) / 2;
    pe_mfma2<<<grid, 256, 0, stream>>>(x, W_in, b_in, W_out, out, batch);
}

// Round 5
// 113.136 us; speedup vs baseline: 1.3985x; 1.3985x over previous
//
#include <hip/hip_runtime.h>

typedef __fp16 half8   __attribute__((ext_vector_type(8)));
typedef __fp16 half2v  __attribute__((ext_vector_type(2)));
typedef float  float4v __attribute__((ext_vector_type(4)));

#define SCALE 2.88539008177792681f   // 2*log2(e): folded into W_in,b_in so MFMA yields a' = 2a*log2(e)

#if defined(__has_builtin) && __has_builtin(__builtin_amdgcn_fdot2)
#define DOT2(a, b, c) __builtin_amdgcn_fdot2((a), (b), (c), false)
#else
#define DOT2(a, b, c) ((c) + (float)(a).x * (float)(b).x + (float)(a).y * (float)(b).y)
#endif

// 2 batch rows per block, grid = batch/2 = 2048 = 8 blocks/CU: all blocks
// co-resident (LDS 8x11.8=94KB<160KB, VGPR 52*8 waves/SIMD fits 512 pool),
// zero block turnover, setup amortized over 2 rows.
// NOTE: no min-waves pin in __launch_bounds__ — R4 showed (256,8) forces the
// allocator to 32 VGPRs -> ~185 MB of scratch-spill HBM traffic, 2x slower.
//
// GEMM1 via MFMA 16x16x32_f16, TRANSPOSED: D[r][win] = W_in*Xwin^T + bias.
//   A = W_in (lane&15 = r-in-tile, k = 8*quad+j; k>=10 zero) — constant, preloaded.
//   B = window data (lane&15 = win-in-tile): lane reads sx[2n+8q .. +7] — im2col free.
//   C = bias (f32-exact add inside the MFMA).
// tanh = 1 - 2*rcp(1+exp2(a')); outer 64->2 via v_dot2_f32_f16 + 2-stage butterfly.
__global__ __launch_bounds__(256) void pe_mfma2(
    const float* __restrict__ x, const float* __restrict__ W_in,
    const float* __restrict__ b_in, const float* __restrict__ W_out,
    float* __restrict__ out, int batch)
{
    __shared__ __align__(16) float sx[2][1056];  // sx[r][i] = x[row_r][(i-4) mod 1024]; tail zero-pad
    __shared__ __align__(16) float sWin[640];
    __shared__ __align__(16) float sWout[128];
    __shared__ __align__(16) float sb[64];

    const int t    = threadIdx.x;
    const int lane = t & 63;
    const int wv   = t >> 6;
    const int col  = lane & 15;
    const int quad = lane >> 4;
    const int row0 = 2 * blockIdx.x;
    const int nrows = (batch - row0 >= 2) ? 2 : 1;

    // ---- stage rows + weights (coalesced float4) ----
    {
        const float* xr0 = x + (size_t)row0 * 1024;
        float4 v0 = reinterpret_cast<const float4*>(xr0)[t];
        reinterpret_cast<float4*>(sx[0] + 4)[t] = v0;
        if (t < 4) { sx[0][t] = xr0[1020 + t]; sx[0][1028 + t] = xr0[t]; }
        if (t >= 8 && t < 32) { sx[0][1024 + t] = 0.f; sx[1][1024 + t] = 0.f; }
        if (nrows == 2) {
            const float* xr1 = xr0 + 1024;
            float4 v1 = reinterpret_cast<const float4*>(xr1)[t];
            reinterpret_cast<float4*>(sx[1] + 4)[t] = v1;
            if (t < 4) { sx[1][t] = xr1[1020 + t]; sx[1][1028 + t] = xr1[t]; }
        }
    }
    if (t < 160)
        reinterpret_cast<float4*>(sWin)[t] = reinterpret_cast<const float4*>(W_in)[t];
    else if (t >= 192 && t < 224)
        reinterpret_cast<float4*>(sWout)[t - 192] = reinterpret_cast<const float4*>(W_out)[t - 192];
    else if (t >= 224 && t < 240)
        reinterpret_cast<float4*>(sb)[t - 224] = reinterpret_cast<const float4*>(b_in)[t - 224];
    __syncthreads();

    // ---- per-lane constant fragments (shared by both rows) ----
    half8  Af[4];        // W_in * SCALE, 4 M-tiles of r
    float4v Cb[4];       // bias * SCALE (f32, exact)
    half2v Wp[4][2][2];  // W_out packed pairs [t4][pair][g], r = 16*t4+4*quad+2*pair
    #pragma unroll
    for (int t4 = 0; t4 < 4; ++t4) {
        const int r = 16 * t4 + col;
        #pragma unroll
        for (int j = 0; j < 8; ++j) {
            const int k = 8 * quad + j;
            Af[t4][j] = (__fp16)((k < 10) ? sWin[r * 10 + k] * SCALE : 0.f);
        }
        const int rb = 16 * t4 + 4 * quad;
        #pragma unroll
        for (int e = 0; e < 4; ++e) Cb[t4][e] = sb[rb + e] * SCALE;
        #pragma unroll
        for (int p = 0; p < 2; ++p) {
            const int r0 = rb + 2 * p;
            #pragma unroll
            for (int g = 0; g < 2; ++g)
                Wp[t4][p][g] = __builtin_amdgcn_cvt_pkrtz(sWout[g * 64 + r0], sWout[g * 64 + r0 + 1]);
        }
    }

    for (int row = 0; row < nrows; ++row) {
        const float* sxr = sx[row];
        float* orow = out + (size_t)(row0 + row) * 1024;

        #pragma unroll 2
        for (int it = 0; it < 8; ++it) {
            const int tile = wv * 8 + it;
            const int n    = tile * 16 + col;      // this lane's window
            const int base = 2 * n + 8 * quad;     // sx index of this lane's k-slice

            half8 Bf;
            #pragma unroll
            for (int p = 0; p < 4; ++p) {          // 4x ds_read_b64
                const float2 xv = *reinterpret_cast<const float2*>(sxr + base + 2 * p);
                const half2v h = __builtin_amdgcn_cvt_pkrtz(xv.x, xv.y);
                Bf[2 * p]     = h.x;
                Bf[2 * p + 1] = h.y;
            }

            float4v D[4];
            #pragma unroll
            for (int t4 = 0; t4 < 4; ++t4)
                D[t4] = __builtin_amdgcn_mfma_f32_16x16x32_f16(Af[t4], Bf, Cb[t4], 0, 0, 0);

            float g0 = 0.f, g1 = 0.f;
            #pragma unroll
            for (int t4 = 0; t4 < 4; ++t4) {
                float th[4];
                #pragma unroll
                for (int e = 0; e < 4; ++e) {
                    const float ex = __builtin_amdgcn_exp2f(D[t4][e]);   // e^{2a}
                    th[e] = fmaf(-2.f, __builtin_amdgcn_rcpf(1.f + ex), 1.f);
                }
                const half2v y01 = __builtin_amdgcn_cvt_pkrtz(th[0], th[1]);
                const half2v y23 = __builtin_amdgcn_cvt_pkrtz(th[2], th[3]);
                g0 = DOT2(y01, Wp[t4][0][0], g0);
                g0 = DOT2(y23, Wp[t4][1][0], g0);
                g1 = DOT2(y01, Wp[t4][0][1], g1);
                g1 = DOT2(y23, Wp[t4][1][1], g1);
            }

            g0 += __shfl_xor(g0, 16, 64);
            g0 += __shfl_xor(g0, 32, 64);
            g1 += __shfl_xor(g1, 16, 64);
            g1 += __shfl_xor(g1, 32, 64);

            if (quad == 0) {
                const float2 xr = *reinterpret_cast<const float2*>(sxr + 4 + 2 * n);
                float2 o;
                o.x = xr.x + g0;
                o.y = xr.y + g1;
                *reinterpret_cast<float2*>(orow + 2 * n) = o;
            }
        }
    }
}

extern "C" void kernel_launch(void* const* d_in, const int* in_sizes, int n_in,
                              void* d_out, int out_size, void* d_ws, size_t ws_size,
                              hipStream_t stream) {
    const float* x     = (const float*)d_in[0];
    const float* W_in  = (const float*)d_in[1];
    const float* b_in  = (const float*)d_in[2];
    const float* W_out = (const float*)d_in[3];
    // d_in[4] = idx — gather is analytically (2n-4+f) mod 1024
    float* out = (float*)d_out;
    const int batch = in_sizes[0] / 1024;
    const int grid  = (batch + 1) / 2;
    pe_mfma2<<<grid, 256, 0, stream>>>(x, W_in, b_in, W_out, out, batch);
}

// Round 6
// 103.739 us; speedup vs baseline: 1.5252x; 1.0906x over previous
//
#include <hip/hip_runtime.h>

typedef __fp16 half8    __attribute__((ext_vector_type(8)));
typedef __fp16 half2v   __attribute__((ext_vector_type(2)));
typedef float  float16v __attribute__((ext_vector_type(16)));

#if defined(__has_builtin) && __has_builtin(__builtin_amdgcn_fdot2)
#define DOT2(a, b, c) __builtin_amdgcn_fdot2((a), (b), (c), false)
#else
#define DOT2(a, b, c) ((c) + (float)(a).x * (float)(b).x + (float)(a).y * (float)(b).y)
#endif

// 4 rows/block, grid = batch/4 = 1024. Per row: 16 tiles of 32 windows
// (MFMA 32x32x16_f16, K=16: taps k=0..9, k=10 carries the BIAS via
// A[m][10]=b_in[m], B[10][n]=1.0 — exact f32 bias, C-operand = 0).
// Transposed GEMM: D[r][win]; C-layout (verified m74/m101): col=lane&31=win,
// row=(reg&3)+8*(reg>>2)+4*(lane>>5). Rows live in only 2 lane-groups ->
// outer-linear reduction is ONE shfl_xor(32) stage.
// tanh via packed-f16 odd polynomial (no trans ops, no div):
//   t = clamp(x,+-3); th = t*(c0 + c1 z + c2 z^2 + c3 z^3 + c4 z^4), z=t*t
// max poly err ~8e-3, tail err 5e-3 — well under the 0.11 threshold.
// NOTE: no min-waves pin (R4: (256,8) pin -> 32 VGPR -> 185MB spill traffic).
__global__ __launch_bounds__(256) void pe_mfma32(
    const float* __restrict__ x, const float* __restrict__ W_in,
    const float* __restrict__ b_in, const float* __restrict__ W_out,
    float* __restrict__ out, int batch)
{
    __shared__ __align__(16) float sx[4][1056];  // sx[r][i] = x[row_r][(i-4) mod 1024]
    __shared__ __align__(16) float sWin[640];
    __shared__ __align__(16) float sWout[128];
    __shared__ __align__(16) float sb[64];

    const int t    = threadIdx.x;
    const int lane = t & 63;
    const int wv   = t >> 6;        // wave 0..3
    const int n32  = lane & 31;     // window-in-tile (B col) AND weight row (A row)
    const int g    = lane >> 5;     // k-group 0/1
    const int row0 = 4 * blockIdx.x;
    const int nrows = (batch - row0 >= 4) ? 4 : (batch - row0);

    // ---- stage rows + weights (coalesced float4) ----
    for (int r = 0; r < nrows; ++r) {
        const float* xr = x + (size_t)(row0 + r) * 1024;
        reinterpret_cast<float4*>(sx[r] + 4)[t] = reinterpret_cast<const float4*>(xr)[t];
        if (t < 4) { sx[r][t] = xr[1020 + t]; sx[r][1028 + t] = xr[t]; }
    }
    if (t < 160)
        reinterpret_cast<float4*>(sWin)[t] = reinterpret_cast<const float4*>(W_in)[t];
    else if (t >= 160 && t < 192)
        reinterpret_cast<float4*>(sWout)[t - 160] = reinterpret_cast<const float4*>(W_out)[t - 160];
    else if (t >= 192 && t < 208)
        reinterpret_cast<float4*>(sb)[t - 192] = reinterpret_cast<const float4*>(b_in)[t - 192];
    __syncthreads();

    // ---- per-lane constant fragments ----
    half8 Af[2];          // A[m][k], m = 32*mf + n32, k = 8*g + j; k==10 -> bias
    #pragma unroll
    for (int mf = 0; mf < 2; ++mf) {
        const int R = 32 * mf + n32;
        #pragma unroll
        for (int j = 0; j < 8; ++j) {
            const int k = 8 * g + j;
            const float w = (k < 10) ? sWin[R * 10 + k] : (k == 10 ? sb[R] : 0.f);
            Af[mf][j] = (__fp16)w;
        }
    }
    half2v Wp[2][8][2];   // W_out pairs: rows (R,R+1), R = 32*mf + 2*(p&1) + 8*(p>>1) + 4*g
    #pragma unroll
    for (int mf = 0; mf < 2; ++mf)
        #pragma unroll
        for (int p = 0; p < 8; ++p) {
            const int R = 32 * mf + ((p & 1) << 1) + 8 * (p >> 1) + 4 * g;
            #pragma unroll
            for (int o = 0; o < 2; ++o)
                Wp[mf][p][o] = __builtin_amdgcn_cvt_pkrtz(sWout[o * 64 + R], sWout[o * 64 + R + 1]);
        }

    const half2v C0 = {(__fp16)0.98931f,     (__fp16)0.98931f};
    const half2v C1 = {(__fp16)-0.26964f,    (__fp16)-0.26964f};
    const half2v C2 = {(__fp16)0.054759f,    (__fp16)0.054759f};
    const half2v C3 = {(__fp16)-0.0057126f,  (__fp16)-0.0057126f};
    const half2v C4 = {(__fp16)0.00022867f,  (__fp16)0.00022867f};
    const half2v HI = {(__fp16)3.0f,  (__fp16)3.0f};
    const half2v LO = {(__fp16)-3.0f, (__fp16)-3.0f};
    const half2v ONE0 = {(__fp16)1.0f, (__fp16)0.0f};
    const half2v ZER0 = {(__fp16)0.0f, (__fp16)0.0f};
    const float16v Zacc = {};

    for (int row = 0; row < nrows; ++row) {
        const float* sxr = sx[row];
        float* orow = out + (size_t)(row0 + row) * 1024;

        #pragma unroll 2
        for (int it = 0; it < 4; ++it) {
            const int tile = wv * 4 + it;
            const int n    = tile * 32 + n32;          // this lane's window
            const int base = 2 * n + 8 * g;            // word index of k-slice start

            // B fragment: 8 k-values; g=1 lanes keep j=0,1 (taps 8,9),
            // j=2 -> 1.0 (bias lane), j>=3 -> 0. Loads of discarded slots are
            // in-bounds garbage, masked by selects after cvt.
            half2v hp[4];
            #pragma unroll
            for (int p = 0; p < 4; ++p) {
                const float2 q = *reinterpret_cast<const float2*>(sxr + base + 2 * p);
                hp[p] = __builtin_amdgcn_cvt_pkrtz(q.x, q.y);
            }
            if (g) { hp[1] = ONE0; hp[2] = ZER0; hp[3] = ZER0; }  // half-wave select (cndmask)
            half8 Bf;
            #pragma unroll
            for (int p = 0; p < 4; ++p) { Bf[2 * p] = hp[p].x; Bf[2 * p + 1] = hp[p].y; }

            float g0 = 0.f, g1 = 0.f;
            #pragma unroll
            for (int mf = 0; mf < 2; ++mf) {
                const float16v D = __builtin_amdgcn_mfma_f32_32x32x16_f16(Af[mf], Bf, Zacc, 0, 0, 0);
                #pragma unroll
                for (int p = 0; p < 8; ++p) {
                    half2v zt = __builtin_amdgcn_cvt_pkrtz(D[2 * p], D[2 * p + 1]);
                    zt = __builtin_elementwise_min(__builtin_elementwise_max(zt, LO), HI);
                    const half2v z2 = zt * zt;
                    half2v P = C4;
                    P = P * z2 + C3;
                    P = P * z2 + C2;
                    P = P * z2 + C1;
                    P = P * z2 + C0;
                    const half2v th = zt * P;
                    g0 = DOT2(th, Wp[mf][p][0], g0);
                    g1 = DOT2(th, Wp[mf][p][1], g1);
                }
            }

            // one-stage cross-group reduction (rows split across lane>>5 only)
            g0 += __shfl_xor(g0, 32, 64);
            g1 += __shfl_xor(g1, 32, 64);

            if (lane < 32) {
                const float2 xr = *reinterpret_cast<const float2*>(sxr + 4 + 2 * n);
                float2 o;
                o.x = xr.x + g0;
                o.y = xr.y + g1;
                *reinterpret_cast<float2*>(orow + 2 * n) = o;   // 32 lanes x 8B contiguous
            }
        }
    }
}

extern "C" void kernel_launch(void* const* d_in, const int* in_sizes, int n_in,
                              void* d_out, int out_size, void* d_ws, size_t ws_size,
                              hipStream_t stream) {
    const float* x     = (const float*)d_in[0];
    const float* W_in  = (const float*)d_in[1];
    const float* b_in  = (const float*)d_in[2];
    const float* W_out = (const float*)d_in[3];
    // d_in[4] = idx — gather is analytically (2n-4+f) mod 1024
    float* out = (float*)d_out;
    const int batch = in_sizes[0] / 1024;
    const int grid  = (batch + 3) / 4;
    pe_mfma32<<<grid, 256, 0, stream>>>(x, W_in, b_in, W_out, out, batch);
}